// Round 17
// baseline (289.934 us; speedup 1.0000x reference)
//
#include <hip/hip_runtime.h>
#include <hip/hip_bf16.h>
#include <hip/hip_fp16.h>
#include <math.h>

#define SLOPE 0.2f
#define CHUNK 16384   // big chunks: 104 blocks -> 104-deep atomic chains (was 416)
#define BCAP 6144     // padded bucket capacity (mean 4352, +27 sigma)

__host__ __device__ static inline int imin(int a, int b) { return a < b ? a : b; }

typedef _Float16 half8 __attribute__((ext_vector_type(8)));
typedef float f32x4 __attribute__((ext_vector_type(4)));

__device__ __forceinline__ unsigned fmap(float f) {
    unsigned u = __float_as_uint(f);
    return (u & 0x80000000u) ? ~u : (u | 0x80000000u);
}
__device__ __forceinline__ float funmap(unsigned u) {
    unsigned v = (u & 0x80000000u) ? (u & 0x7FFFFFFFu) : ~u;
    return __uint_as_float(v);
}

// ---------------- MFMA GEMM + attention dots + global AS-max (body) --------
template<int HC, typename TIN>
__device__ __forceinline__
void gemm_att_body(int bid, int nblk,
                   const TIN* __restrict__ x, const float* __restrict__ W,
                   const float* __restrict__ att_s, const float* __restrict__ att_d,
                   __half* __restrict__ h, float* __restrict__ a_s,
                   float* __restrict__ a_d, unsigned* __restrict__ Ms, int N) {
    constexpr int H = HC / 64;
    constexpr int CT = HC / 16;           // col tiles (8 or 4)
    __shared__ half8 blds[CT * 4 * 64];   // W fragments (32KB / 16KB)
    __shared__ half8 xlds[4 * 4 * 64];    // x fragments (16KB)

    const int tid = threadIdx.x;
    const int lane = tid & 63;
    const int wid = tid >> 6;

    for (int u = tid; u < HC * 16; u += 256) {
        int col = u & (HC - 1), k8 = u / HC;
        half8 v;
#pragma unroll
        for (int j = 0; j < 8; ++j) v[j] = (_Float16)W[(k8 * 8 + j) * HC + col];
        blds[((col >> 4) * 4 + (k8 >> 2)) * 64 + (k8 & 3) * 16 + (col & 15)] = v;
    }

    float asv[CT], adv[CT];
#pragma unroll
    for (int ct = 0; ct < CT; ++ct) {
        asv[ct] = att_s[ct * 16 + (lane & 15)];
        adv[ct] = att_d[ct * 16 + (lane & 15)];
    }
    float ms0 = -INFINITY, ms1 = -INFINITY;

    const int ntiles = (N + 63) >> 6;
    for (int t = bid; t < ntiles; t += nblk) {
        const int row0 = t << 6;
        __syncthreads();
#pragma unroll
        for (int i = 0; i < 4; ++i) {
            int u = tid + 256 * i;
            int r = u >> 4, k8 = u & 15;
            int row = row0 + r;
            half8 v;
            if (row < N) {
                if (sizeof(TIN) == 4) {
                    float4 f0 = ((const float4*)x)[(size_t)row * 32 + k8 * 2];
                    float4 f1 = ((const float4*)x)[(size_t)row * 32 + k8 * 2 + 1];
                    v[0] = (_Float16)f0.x; v[1] = (_Float16)f0.y;
                    v[2] = (_Float16)f0.z; v[3] = (_Float16)f0.w;
                    v[4] = (_Float16)f1.x; v[5] = (_Float16)f1.y;
                    v[6] = (_Float16)f1.z; v[7] = (_Float16)f1.w;
                } else {
                    v = ((const half8*)x)[(size_t)row * 16 + k8];
                }
            } else {
#pragma unroll
                for (int j = 0; j < 8; ++j) v[j] = (_Float16)0.f;
            }
            xlds[((r >> 4) * 4 + (k8 >> 2)) * 64 + (k8 & 3) * 16 + (r & 15)] = v;
        }
        __syncthreads();

        f32x4 acc[CT];
#pragma unroll
        for (int ct = 0; ct < CT; ++ct) acc[ct] = f32x4{0.f, 0.f, 0.f, 0.f};
        half8 afrag[4];
#pragma unroll
        for (int s = 0; s < 4; ++s) afrag[s] = xlds[(wid * 4 + s) * 64 + lane];
#pragma unroll
        for (int ct = 0; ct < CT; ++ct)
#pragma unroll
            for (int s = 0; s < 4; ++s)
                acc[ct] = __builtin_amdgcn_mfma_f32_16x16x32_f16(
                    afrag[s], blds[(ct * 4 + s) * 64 + lane], acc[ct], 0, 0, 0);

#pragma unroll
        for (int q = 0; q < 4; ++q) {
            int row = row0 + wid * 16 + (lane >> 4) * 4 + q;
            bool ok = row < N;
#pragma unroll
            for (int ct = 0; ct < CT; ++ct)
                if (ok) h[(size_t)row * HC + ct * 16 + (lane & 15)] =
                    __float2half((float)acc[ct][q]);
            float vs0 = 0.f, vd0 = 0.f, vs1 = 0.f, vd1 = 0.f;
#pragma unroll
            for (int ct = 0; ct < CT; ++ct) {
                float a = acc[ct][q];
                if (H == 2 && ct >= CT / 2) { vs1 = fmaf(a, asv[ct], vs1); vd1 = fmaf(a, adv[ct], vd1); }
                else                        { vs0 = fmaf(a, asv[ct], vs0); vd0 = fmaf(a, adv[ct], vd0); }
            }
#pragma unroll
            for (int off = 1; off < 16; off <<= 1) {
                vs0 += __shfl_xor(vs0, off); vd0 += __shfl_xor(vd0, off);
                if (H == 2) { vs1 += __shfl_xor(vs1, off); vd1 += __shfl_xor(vd1, off); }
            }
            if (ok) {
                ms0 = fmaxf(ms0, vs0);
                if (H == 2) ms1 = fmaxf(ms1, vs1);
                if ((lane & 15) == 0) {
                    if (H == 2) {
                        ((float2*)a_s)[row] = make_float2(vs0, vs1);
                        ((float2*)a_d)[row] = make_float2(vd0, vd1);
                    } else {
                        a_s[row] = vs0;
                        a_d[row] = vd0;
                    }
                }
            }
        }
    }
#pragma unroll
    for (int off = 1; off < 64; off <<= 1) {
        ms0 = fmaxf(ms0, __shfl_xor(ms0, off));
        if (H == 2) ms1 = fmaxf(ms1, __shfl_xor(ms1, off));
    }
    if (lane == 0) {
        atomicMax(&Ms[0], fmap(ms0));
        if (H == 2) atomicMax(&Ms[1], fmap(ms1));
    }
}

// ---------------- padded-bucket scatter body (no pre-histogram) ------------
__device__ __forceinline__
void bscatter_body(int bid, const int* __restrict__ ei, int E, int Etot,
                   int* __restrict__ bnext, unsigned* __restrict__ pairs, int nb) {
    __shared__ int lcnt[512];
    __shared__ int lbase[512];
    const int t = threadIdx.x;
    const int c0 = bid * CHUNK;
    const int lim = imin(CHUNK, Etot - c0);

    for (int i = t; i < nb; i += 256) lcnt[i] = 0;
    __syncthreads();
    for (int j = t; j < lim; j += 256) {
        int e = c0 + j;
        int dst = (e < E) ? ei[E + e] : (e - E);
        atomicAdd(&lcnt[dst >> 8], 1);
    }
    __syncthreads();
    for (int i = t; i < nb; i += 256) {
        int c = lcnt[i];
        lbase[i] = c ? atomicAdd(&bnext[i], c) : 0;
        lcnt[i] = 0;   // reuse as cursor
    }
    __syncthreads();
    for (int j = t; j < lim; j += 256) {
        int e = c0 + j;
        int src = (e < E) ? ei[e] : (e - E);
        int dst = (e < E) ? ei[E + e] : (e - E);
        int b = dst >> 8;
        int off = atomicAdd(&lcnt[b], 1);
        pairs[(size_t)b * BCAP + lbase[b] + off] =
            ((unsigned)(dst & 255) << 24) | (unsigned)src;
    }
}

// ---------------- fat kernel: bscatter (blocks [0,cb)) || gemm1 ------------
__global__ __launch_bounds__(256, 2)
void fat1_k(const int* __restrict__ ei, int E, int Etot,
            int* __restrict__ bnext, unsigned* __restrict__ pairs, int nb, int cb,
            const float* __restrict__ x, const float* __restrict__ W,
            const float* __restrict__ att_s, const float* __restrict__ att_d,
            __half* __restrict__ h, float* __restrict__ a_s,
            float* __restrict__ a_d, unsigned* __restrict__ Ms, int N, int gblk) {
    if ((int)blockIdx.x < cb)
        bscatter_body(blockIdx.x, ei, E, Etot, bnext, pairs, nb);
    else
        gemm_att_body<128, float>(blockIdx.x - cb, gblk, x, W, att_s, att_d,
                                  h, a_s, a_d, Ms, N);
}

__global__ __launch_bounds__(256, 2)
void gemm2_k(const __half* __restrict__ x, const float* __restrict__ W,
             const float* __restrict__ att_s, const float* __restrict__ att_d,
             __half* __restrict__ h, float* __restrict__ a_s,
             float* __restrict__ a_d, unsigned* __restrict__ Ms, int N) {
    gemm_att_body<64, __half>(blockIdx.x, gridDim.x, x, W, att_s, att_d,
                              h, a_s, a_d, Ms, N);
}

// one block per bucket: self-computed base (prefix sum of bnext) -> rowptr +
// packed colsrc
__global__ __launch_bounds__(256)
void fine_k(const unsigned* __restrict__ pairs, const int* __restrict__ bnext,
            int* __restrict__ rowptr, int* __restrict__ colsrc,
            int nb, int N, int Etot) {
    __shared__ int sm[256];
    __shared__ int lnext[256];
    __shared__ int red[256];
    const int b = blockIdx.x, t = threadIdx.x;
    const int cnt = bnext[b];
    const size_t pbase = (size_t)b * BCAP;

    // global base = prefix sum of bnext[0..b)
    int pacc = 0;
    for (int i = t; i < b; i += 256) pacc += bnext[i];
    red[t] = pacc; __syncthreads();
    for (int off = 128; off; off >>= 1) {
        if (t < off) red[t] += red[t + off];
        __syncthreads();
    }
    const int gbase = red[0];
    if (b == 0 && t == 0) rowptr[N] = Etot;

    lnext[t] = 0;
    __syncthreads();
    for (int i = t; i < cnt; i += 256)
        atomicAdd(&lnext[pairs[pbase + i] >> 24], 1);
    __syncthreads();
    int v = lnext[t];
    sm[t] = v; __syncthreads();
    for (int off = 1; off < 256; off <<= 1) {
        int u = (t >= off) ? sm[t - off] : 0;
        __syncthreads();
        sm[t] += u;
        __syncthreads();
    }
    int excl = sm[t] - v;
    int node = (b << 8) + t;
    if (node < N) rowptr[node] = gbase + excl;
    lnext[t] = excl;
    __syncthreads();
    for (int i = t; i < cnt; i += 256) {
        unsigned pr = pairs[pbase + i];
        int p = atomicAdd(&lnext[pr >> 24], 1);
        colsrc[gbase + p] = (int)(pr & 0xFFFFFFu);
    }
}

// ---------------- per-node aggregation, edge-parallel lane groups ----------
template<bool ELU>
__global__ __launch_bounds__(256)
void node_aggr2(const int* __restrict__ rowptr, const int* __restrict__ colsrc,
                const float* __restrict__ a_s, const float* __restrict__ a_d,
                const __half* __restrict__ h, const float* __restrict__ bias,
                const unsigned* __restrict__ Ms, __half* __restrict__ out, int N) {
    int gw = (blockIdx.x * 256 + threadIdx.x) >> 6;
    int lane = threadIdx.x & 63;
    int nw = (gridDim.x * 256) >> 6;
    const int g = lane >> 4;
    const int p = lane & 15;
    const float AS0 = funmap(Ms[0]);
    const float AS1 = funmap(Ms[1]);
    float4 bv0 = ((const float4*)bias)[p * 2];
    float4 bv1 = ((const float4*)bias)[p * 2 + 1];

    for (int n = gw; n < N; n += nw) {
        const int b = rowptr[n], deg = rowptr[n + 1] - b;
        const float2 adn = ((const float2*)a_d)[n];
        float M0 = AS0 + adn.x; M0 = M0 > 0.f ? M0 : SLOPE * M0;
        float M1 = AS1 + adn.y; M1 = M1 > 0.f ? M1 : SLOPE * M1;
        float4 acc0 = make_float4(0.f, 0.f, 0.f, 0.f);
        float4 acc1 = make_float4(0.f, 0.f, 0.f, 0.f);
        float den = 0.f;

        for (int c = 0; c < deg; c += 64) {
            int ii = c + lane;
            int src_r = 0;
            float w0_r = 0.f, w1_r = 0.f;
            if (ii < deg) {
                src_r = colsrc[b + ii];
                float2 as = ((const float2*)a_s)[src_r];
                float s0 = as.x + adn.x; s0 = s0 > 0.f ? s0 : SLOPE * s0;
                float s1 = as.y + adn.y; s1 = s1 > 0.f ? s1 : SLOPE * s1;
                w0_r = __expf(s0 - M0);
                w1_r = __expf(s1 - M1);
            }
            int lim = (deg - c < 64) ? (deg - c) : 64;
#pragma unroll 2
            for (int i = 0; i < lim; i += 4) {
                int e = i + g;
                int src = __shfl(src_r, e);
                float w0b = __shfl(w0_r, e);
                float w1b = __shfl(w1_r, e);
                float w = (p < 8) ? w0b : w1b;
                den += w;
                uint4 hv = ((const uint4*)h)[(size_t)src * 16 + p];
                float2 f0 = __half22float2(*(__half2*)&hv.x);
                float2 f1 = __half22float2(*(__half2*)&hv.y);
                float2 f2 = __half22float2(*(__half2*)&hv.z);
                float2 f3 = __half22float2(*(__half2*)&hv.w);
                acc0.x = fmaf(w, f0.x, acc0.x); acc0.y = fmaf(w, f0.y, acc0.y);
                acc0.z = fmaf(w, f1.x, acc0.z); acc0.w = fmaf(w, f1.y, acc0.w);
                acc1.x = fmaf(w, f2.x, acc1.x); acc1.y = fmaf(w, f2.y, acc1.y);
                acc1.z = fmaf(w, f3.x, acc1.z); acc1.w = fmaf(w, f3.y, acc1.w);
            }
        }
#pragma unroll
        for (int off = 16; off <= 32; off <<= 1) {
            acc0.x += __shfl_xor(acc0.x, off); acc0.y += __shfl_xor(acc0.y, off);
            acc0.z += __shfl_xor(acc0.z, off); acc0.w += __shfl_xor(acc0.w, off);
            acc1.x += __shfl_xor(acc1.x, off); acc1.y += __shfl_xor(acc1.y, off);
            acc1.z += __shfl_xor(acc1.z, off); acc1.w += __shfl_xor(acc1.w, off);
            den    += __shfl_xor(den, off);
        }
        if (lane < 16) {
            float inv = 1.f / den;
            float4 o0, o1;
            o0.x = acc0.x * inv + bv0.x; o0.y = acc0.y * inv + bv0.y;
            o0.z = acc0.z * inv + bv0.z; o0.w = acc0.w * inv + bv0.w;
            o1.x = acc1.x * inv + bv1.x; o1.y = acc1.y * inv + bv1.y;
            o1.z = acc1.z * inv + bv1.z; o1.w = acc1.w * inv + bv1.w;
            if (ELU) {
                o0.x = o0.x > 0.f ? o0.x : expm1f(o0.x);
                o0.y = o0.y > 0.f ? o0.y : expm1f(o0.y);
                o0.z = o0.z > 0.f ? o0.z : expm1f(o0.z);
                o0.w = o0.w > 0.f ? o0.w : expm1f(o0.w);
                o1.x = o1.x > 0.f ? o1.x : expm1f(o1.x);
                o1.y = o1.y > 0.f ? o1.y : expm1f(o1.y);
                o1.z = o1.z > 0.f ? o1.z : expm1f(o1.z);
                o1.w = o1.w > 0.f ? o1.w : expm1f(o1.w);
            }
            __half2 q0 = __floats2half2_rn(o0.x, o0.y);
            __half2 q1 = __floats2half2_rn(o0.z, o0.w);
            __half2 q2 = __floats2half2_rn(o1.x, o1.y);
            __half2 q3 = __floats2half2_rn(o1.z, o1.w);
            uint4 pk;
            pk.x = *(unsigned*)&q0; pk.y = *(unsigned*)&q1;
            pk.z = *(unsigned*)&q2; pk.w = *(unsigned*)&q3;
            ((uint4*)out)[(size_t)n * 16 + p] = pk;
        }
    }
}

__global__ __launch_bounds__(256)
void node_aggr1(const int* __restrict__ rowptr, const int* __restrict__ colsrc,
                const float* __restrict__ a_s, const float* __restrict__ a_d,
                const __half* __restrict__ h, const float* __restrict__ bias,
                const unsigned* __restrict__ Ms, float* __restrict__ out, int N) {
    int gw = (blockIdx.x * 256 + threadIdx.x) >> 6;
    int lane = threadIdx.x & 63;
    int nw = (gridDim.x * 256) >> 6;
    const int g = lane >> 3;
    const int p = lane & 7;
    const float AS = funmap(Ms[0]);
    float4 bv0 = ((const float4*)bias)[p * 2];
    float4 bv1 = ((const float4*)bias)[p * 2 + 1];

    for (int n = gw; n < N; n += nw) {
        const int b = rowptr[n], deg = rowptr[n + 1] - b;
        const float adn = a_d[n];
        float M = AS + adn; M = M > 0.f ? M : SLOPE * M;
        float den = 0.f;
        float4 acc0 = make_float4(0.f, 0.f, 0.f, 0.f);
        float4 acc1 = make_float4(0.f, 0.f, 0.f, 0.f);

        for (int c = 0; c < deg; c += 64) {
            int ii = c + lane;
            int src_r = 0;
            float w_r = 0.f;
            if (ii < deg) {
                src_r = colsrc[b + ii];
                float s = a_s[src_r] + adn;
                s = s > 0.f ? s : SLOPE * s;
                w_r = __expf(s - M);
            }
            int lim = (deg - c < 64) ? (deg - c) : 64;
#pragma unroll 2
            for (int i = 0; i < lim; i += 8) {
                int e = i + g;
                int src = __shfl(src_r, e);
                float w = __shfl(w_r, e);
                den += w;
                uint4 hv = ((const uint4*)h)[(size_t)src * 8 + p];
                float2 f0 = __half22float2(*(__half2*)&hv.x);
                float2 f1 = __half22float2(*(__half2*)&hv.y);
                float2 f2 = __half22float2(*(__half2*)&hv.z);
                float2 f3 = __half22float2(*(__half2*)&hv.w);
                acc0.x = fmaf(w, f0.x, acc0.x); acc0.y = fmaf(w, f0.y, acc0.y);
                acc0.z = fmaf(w, f1.x, acc0.z); acc0.w = fmaf(w, f1.y, acc0.w);
                acc1.x = fmaf(w, f2.x, acc1.x); acc1.y = fmaf(w, f2.y, acc1.y);
                acc1.z = fmaf(w, f3.x, acc1.z); acc1.w = fmaf(w, f3.y, acc1.w);
            }
        }
#pragma unroll
        for (int off = 8; off <= 32; off <<= 1) {
            acc0.x += __shfl_xor(acc0.x, off); acc0.y += __shfl_xor(acc0.y, off);
            acc0.z += __shfl_xor(acc0.z, off); acc0.w += __shfl_xor(acc0.w, off);
            acc1.x += __shfl_xor(acc1.x, off); acc1.y += __shfl_xor(acc1.y, off);
            acc1.z += __shfl_xor(acc1.z, off); acc1.w += __shfl_xor(acc1.w, off);
            den    += __shfl_xor(den, off);
        }
        if (lane < 8) {
            float inv = 1.f / den;
            float4 o0, o1;
            o0.x = acc0.x * inv + bv0.x; o0.y = acc0.y * inv + bv0.y;
            o0.z = acc0.z * inv + bv0.z; o0.w = acc0.w * inv + bv0.w;
            o1.x = acc1.x * inv + bv1.x; o1.y = acc1.y * inv + bv1.y;
            o1.z = acc1.z * inv + bv1.z; o1.w = acc1.w * inv + bv1.w;
            ((float4*)out)[(size_t)n * 16 + p * 2]     = o0;
            ((float4*)out)[(size_t)n * 16 + p * 2 + 1] = o1;
        }
    }
}

extern "C" void kernel_launch(void* const* d_in, const int* in_sizes, int n_in,
                              void* d_out, int out_size, void* d_ws, size_t ws_size,
                              hipStream_t stream) {
    const float* x   = (const float*)d_in[0];
    const int*   ei  = (const int*)d_in[1];
    const float* W1  = (const float*)d_in[2];
    const float* as1 = (const float*)d_in[3];
    const float* ad1 = (const float*)d_in[4];
    const float* b1  = (const float*)d_in[5];
    const float* W2  = (const float*)d_in[6];
    const float* as2 = (const float*)d_in[7];
    const float* ad2 = (const float*)d_in[8];
    const float* b2  = (const float*)d_in[9];
    float* out = (float*)d_out;

    const int N = out_size / 64;          // 100000
    const int E = in_sizes[1] / 2;        // 1600000
    const int Etot = E + N;
    const int nb = (N + 255) >> 8;        // 391

    float* ws   = (float*)d_ws;
    __half* h1  = (__half*)ws;
    __half* h1e = (__half*)(ws + (size_t)N * 64);
    float* a_s1 = ws + (size_t)N * 128;
    float* a_d1 = a_s1 + (size_t)N * 2;
    float* a_s2 = a_d1 + (size_t)N * 2;
    float* a_d2 = a_s2 + (size_t)N;
    int* rowptr = (int*)(a_d2 + (size_t)N);
    int* bnext  = rowptr + (N + 1);
    unsigned* Ms = (unsigned*)(bnext + 512);   // [0,1]=layer1, [2]=layer2
    int* colsrc = (int*)(Ms + 4);
    unsigned* pairs = (unsigned*)(colsrc + Etot);   // nb*BCAP u32 (~9.6MB)

    // zero bnext (512) + Ms (4) in one memset
    (void)hipMemsetAsync(bnext, 0, (512 + 4) * 4, stream);

    int cb = (Etot + CHUNK - 1) / CHUNK;        // 104
    const int GB = 512;                         // gemm blocks in fat kernel

    // ---- fat: bucket scatter || layer-1 MFMA GEMM ----
    fat1_k<<<dim3(cb + GB), dim3(256), 0, stream>>>(
        ei, E, Etot, bnext, pairs, nb, cb,
        x, W1, as1, ad1, h1, a_s1, a_d1, Ms, N, GB);
    fine_k<<<dim3(nb), dim3(256), 0, stream>>>(
        pairs, bnext, rowptr, colsrc, nb, N, Etot);

    int ab = imin((N + 3) / 4, 25000);

    // ---- layer 1 aggregation ----
    node_aggr2<true><<<dim3(ab), dim3(256), 0, stream>>>(
        rowptr, colsrc, a_s1, a_d1, h1, b1, Ms, h1e, N);

    // ---- layer 2 ----
    __half* h2 = h1;   // h1 dead after node_aggr2
    gemm2_k<<<dim3(512), dim3(256), 0, stream>>>(
        h1e, W2, as2, ad2, h2, a_s2, a_d2, Ms + 2, N);
    node_aggr1<<<dim3(ab), dim3(256), 0, stream>>>(
        rowptr, colsrc, a_s2, a_d2, h2, b2, Ms + 2, out, N);
}

// Round 18
// 273.413 us; speedup vs baseline: 1.0604x; 1.0604x over previous
//
#include <hip/hip_runtime.h>
#include <hip/hip_bf16.h>
#include <hip/hip_fp16.h>
#include <math.h>

#define SLOPE 0.2f
#define CHUNK 4096
#define BCAP 6144     // padded bucket capacity (mean 4352, +27 sigma)

__host__ __device__ static inline int imin(int a, int b) { return a < b ? a : b; }

typedef _Float16 half8 __attribute__((ext_vector_type(8)));
typedef float f32x4 __attribute__((ext_vector_type(4)));

__device__ __forceinline__ unsigned fmap(float f) {
    unsigned u = __float_as_uint(f);
    return (u & 0x80000000u) ? ~u : (u | 0x80000000u);
}
__device__ __forceinline__ float funmap(unsigned u) {
    unsigned v = (u & 0x80000000u) ? (u & 0x7FFFFFFFu) : ~u;
    return __uint_as_float(v);
}

// ---------------- MFMA GEMM + attention dots + global AS-max (body) --------
template<int HC, typename TIN>
__device__ __forceinline__
void gemm_att_body(int bid, int nblk,
                   const TIN* __restrict__ x, const float* __restrict__ W,
                   const float* __restrict__ att_s, const float* __restrict__ att_d,
                   __half* __restrict__ h, float* __restrict__ a_s,
                   float* __restrict__ a_d, unsigned* __restrict__ Ms, int N) {
    constexpr int H = HC / 64;
    constexpr int CT = HC / 16;           // col tiles (8 or 4)
    __shared__ half8 blds[CT * 4 * 64];   // W fragments (32KB / 16KB)
    __shared__ half8 xlds[4 * 4 * 64];    // x fragments (16KB)

    const int tid = threadIdx.x;
    const int lane = tid & 63;
    const int wid = tid >> 6;

    for (int u = tid; u < HC * 16; u += 256) {
        int col = u & (HC - 1), k8 = u / HC;
        half8 v;
#pragma unroll
        for (int j = 0; j < 8; ++j) v[j] = (_Float16)W[(k8 * 8 + j) * HC + col];
        blds[((col >> 4) * 4 + (k8 >> 2)) * 64 + (k8 & 3) * 16 + (col & 15)] = v;
    }

    float asv[CT], adv[CT];
#pragma unroll
    for (int ct = 0; ct < CT; ++ct) {
        asv[ct] = att_s[ct * 16 + (lane & 15)];
        adv[ct] = att_d[ct * 16 + (lane & 15)];
    }
    float ms0 = -INFINITY, ms1 = -INFINITY;

    const int ntiles = (N + 63) >> 6;
    for (int t = bid; t < ntiles; t += nblk) {
        const int row0 = t << 6;
        __syncthreads();
#pragma unroll
        for (int i = 0; i < 4; ++i) {
            int u = tid + 256 * i;
            int r = u >> 4, k8 = u & 15;
            int row = row0 + r;
            half8 v;
            if (row < N) {
                if (sizeof(TIN) == 4) {
                    float4 f0 = ((const float4*)x)[(size_t)row * 32 + k8 * 2];
                    float4 f1 = ((const float4*)x)[(size_t)row * 32 + k8 * 2 + 1];
                    v[0] = (_Float16)f0.x; v[1] = (_Float16)f0.y;
                    v[2] = (_Float16)f0.z; v[3] = (_Float16)f0.w;
                    v[4] = (_Float16)f1.x; v[5] = (_Float16)f1.y;
                    v[6] = (_Float16)f1.z; v[7] = (_Float16)f1.w;
                } else {
                    v = ((const half8*)x)[(size_t)row * 16 + k8];
                }
            } else {
#pragma unroll
                for (int j = 0; j < 8; ++j) v[j] = (_Float16)0.f;
            }
            xlds[((r >> 4) * 4 + (k8 >> 2)) * 64 + (k8 & 3) * 16 + (r & 15)] = v;
        }
        __syncthreads();

        f32x4 acc[CT];
#pragma unroll
        for (int ct = 0; ct < CT; ++ct) acc[ct] = f32x4{0.f, 0.f, 0.f, 0.f};
        half8 afrag[4];
#pragma unroll
        for (int s = 0; s < 4; ++s) afrag[s] = xlds[(wid * 4 + s) * 64 + lane];
#pragma unroll
        for (int ct = 0; ct < CT; ++ct)
#pragma unroll
            for (int s = 0; s < 4; ++s)
                acc[ct] = __builtin_amdgcn_mfma_f32_16x16x32_f16(
                    afrag[s], blds[(ct * 4 + s) * 64 + lane], acc[ct], 0, 0, 0);

#pragma unroll
        for (int q = 0; q < 4; ++q) {
            int row = row0 + wid * 16 + (lane >> 4) * 4 + q;
            bool ok = row < N;
#pragma unroll
            for (int ct = 0; ct < CT; ++ct)
                if (ok) h[(size_t)row * HC + ct * 16 + (lane & 15)] =
                    __float2half((float)acc[ct][q]);
            float vs0 = 0.f, vd0 = 0.f, vs1 = 0.f, vd1 = 0.f;
#pragma unroll
            for (int ct = 0; ct < CT; ++ct) {
                float a = acc[ct][q];
                if (H == 2 && ct >= CT / 2) { vs1 = fmaf(a, asv[ct], vs1); vd1 = fmaf(a, adv[ct], vd1); }
                else                        { vs0 = fmaf(a, asv[ct], vs0); vd0 = fmaf(a, adv[ct], vd0); }
            }
#pragma unroll
            for (int off = 1; off < 16; off <<= 1) {
                vs0 += __shfl_xor(vs0, off); vd0 += __shfl_xor(vd0, off);
                if (H == 2) { vs1 += __shfl_xor(vs1, off); vd1 += __shfl_xor(vd1, off); }
            }
            if (ok) {
                ms0 = fmaxf(ms0, vs0);
                if (H == 2) ms1 = fmaxf(ms1, vs1);
                if ((lane & 15) == 0) {
                    if (H == 2) {
                        ((float2*)a_s)[row] = make_float2(vs0, vs1);
                        ((float2*)a_d)[row] = make_float2(vd0, vd1);
                    } else {
                        a_s[row] = vs0;
                        a_d[row] = vd0;
                    }
                }
            }
        }
    }
#pragma unroll
    for (int off = 1; off < 64; off <<= 1) {
        ms0 = fmaxf(ms0, __shfl_xor(ms0, off));
        if (H == 2) ms1 = fmaxf(ms1, __shfl_xor(ms1, off));
    }
    if (lane == 0) {
        atomicMax(&Ms[0], fmap(ms0));
        if (H == 2) atomicMax(&Ms[1], fmap(ms1));
    }
}

// ---------------- padded-bucket scatter body (no pre-histogram) ------------
__device__ __forceinline__
void bscatter_body(int bid, const int* __restrict__ ei, int E, int Etot,
                   int* __restrict__ bnext, unsigned* __restrict__ pairs, int nb) {
    __shared__ int lcnt[512];
    __shared__ int lbase[512];
    const int t = threadIdx.x;
    const int c0 = bid * CHUNK;
    const int lim = imin(CHUNK, Etot - c0);

    for (int i = t; i < nb; i += 256) lcnt[i] = 0;
    __syncthreads();
    for (int j = t; j < lim; j += 256) {
        int e = c0 + j;
        int dst = (e < E) ? ei[E + e] : (e - E);
        atomicAdd(&lcnt[dst >> 8], 1);
    }
    __syncthreads();
    for (int i = t; i < nb; i += 256) {
        int c = lcnt[i];
        lbase[i] = c ? atomicAdd(&bnext[i], c) : 0;
        lcnt[i] = 0;   // reuse as cursor
    }
    __syncthreads();
    for (int j = t; j < lim; j += 256) {
        int e = c0 + j;
        int src = (e < E) ? ei[e] : (e - E);
        int dst = (e < E) ? ei[E + e] : (e - E);
        int b = dst >> 8;
        int off = atomicAdd(&lcnt[b], 1);
        pairs[(size_t)b * BCAP + lbase[b] + off] =
            ((unsigned)(dst & 255) << 24) | (unsigned)src;
    }
}

// ---------------- fat kernel: bscatter (blocks [0,cb)) || gemm1 ------------
__global__ __launch_bounds__(256, 2)
void fat1_k(const int* __restrict__ ei, int E, int Etot,
            int* __restrict__ bnext, unsigned* __restrict__ pairs, int nb, int cb,
            const float* __restrict__ x, const float* __restrict__ W,
            const float* __restrict__ att_s, const float* __restrict__ att_d,
            __half* __restrict__ h, float* __restrict__ a_s,
            float* __restrict__ a_d, unsigned* __restrict__ Ms, int N, int gblk) {
    if ((int)blockIdx.x < cb)
        bscatter_body(blockIdx.x, ei, E, Etot, bnext, pairs, nb);
    else
        gemm_att_body<128, float>(blockIdx.x - cb, gblk, x, W, att_s, att_d,
                                  h, a_s, a_d, Ms, N);
}

__global__ __launch_bounds__(256, 2)
void gemm2_k(const __half* __restrict__ x, const float* __restrict__ W,
             const float* __restrict__ att_s, const float* __restrict__ att_d,
             __half* __restrict__ h, float* __restrict__ a_s,
             float* __restrict__ a_d, unsigned* __restrict__ Ms, int N) {
    gemm_att_body<64, __half>(blockIdx.x, gridDim.x, x, W, att_s, att_d,
                              h, a_s, a_d, Ms, N);
}

// one block per bucket, 1024 threads (16 waves -> latency hiding):
// self-computed base (prefix sum of bnext) -> rowptr + packed colsrc
__global__ __launch_bounds__(1024)
void fine_k(const unsigned* __restrict__ pairs, const int* __restrict__ bnext,
            int* __restrict__ rowptr, int* __restrict__ colsrc,
            int nb, int N, int Etot) {
    __shared__ int sm[256];
    __shared__ int lnext[256];
    __shared__ int red[1024];
    const int b = blockIdx.x, t = threadIdx.x;
    const int cnt = bnext[b];
    const size_t pbase = (size_t)b * BCAP;

    // global base = prefix sum of bnext[0..b)
    int pacc = 0;
    for (int i = t; i < b; i += 1024) pacc += bnext[i];
    red[t] = pacc; __syncthreads();
    for (int off = 512; off; off >>= 1) {
        if (t < off) red[t] += red[t + off];
        __syncthreads();
    }
    const int gbase = red[0];
    if (b == 0 && t == 0) rowptr[N] = Etot;

    if (t < 256) lnext[t] = 0;
    __syncthreads();
    for (int i = t; i < cnt; i += 1024)
        atomicAdd(&lnext[pairs[pbase + i] >> 24], 1);
    __syncthreads();
    int v = (t < 256) ? lnext[t] : 0;
    if (t < 256) sm[t] = v;
    __syncthreads();
    for (int off = 1; off < 256; off <<= 1) {
        int u = (t >= off && t < 256) ? sm[t - off] : 0;
        __syncthreads();
        if (t < 256) sm[t] += u;
        __syncthreads();
    }
    if (t < 256) {
        int excl = sm[t] - v;
        int node = (b << 8) + t;
        if (node < N) rowptr[node] = gbase + excl;
        lnext[t] = excl;
    }
    __syncthreads();
    for (int i = t; i < cnt; i += 1024) {
        unsigned pr = pairs[pbase + i];
        int p = atomicAdd(&lnext[pr >> 24], 1);
        colsrc[gbase + p] = (int)(pr & 0xFFFFFFu);
    }
}

// ---------------- per-node aggregation, edge-parallel lane groups ----------
template<bool ELU>
__global__ __launch_bounds__(256)
void node_aggr2(const int* __restrict__ rowptr, const int* __restrict__ colsrc,
                const float* __restrict__ a_s, const float* __restrict__ a_d,
                const __half* __restrict__ h, const float* __restrict__ bias,
                const unsigned* __restrict__ Ms, __half* __restrict__ out, int N) {
    int gw = (blockIdx.x * 256 + threadIdx.x) >> 6;
    int lane = threadIdx.x & 63;
    int nw = (gridDim.x * 256) >> 6;
    const int g = lane >> 4;
    const int p = lane & 15;
    const float AS0 = funmap(Ms[0]);
    const float AS1 = funmap(Ms[1]);
    float4 bv0 = ((const float4*)bias)[p * 2];
    float4 bv1 = ((const float4*)bias)[p * 2 + 1];

    for (int n = gw; n < N; n += nw) {
        const int b = rowptr[n], deg = rowptr[n + 1] - b;
        const float2 adn = ((const float2*)a_d)[n];
        float M0 = AS0 + adn.x; M0 = M0 > 0.f ? M0 : SLOPE * M0;
        float M1 = AS1 + adn.y; M1 = M1 > 0.f ? M1 : SLOPE * M1;
        float4 acc0 = make_float4(0.f, 0.f, 0.f, 0.f);
        float4 acc1 = make_float4(0.f, 0.f, 0.f, 0.f);
        float den = 0.f;

        for (int c = 0; c < deg; c += 64) {
            int ii = c + lane;
            int src_r = 0;
            float w0_r = 0.f, w1_r = 0.f;
            if (ii < deg) {
                src_r = colsrc[b + ii];
                float2 as = ((const float2*)a_s)[src_r];
                float s0 = as.x + adn.x; s0 = s0 > 0.f ? s0 : SLOPE * s0;
                float s1 = as.y + adn.y; s1 = s1 > 0.f ? s1 : SLOPE * s1;
                w0_r = __expf(s0 - M0);
                w1_r = __expf(s1 - M1);
            }
            int lim = (deg - c < 64) ? (deg - c) : 64;
#pragma unroll 2
            for (int i = 0; i < lim; i += 4) {
                int e = i + g;
                int src = __shfl(src_r, e);
                float w0b = __shfl(w0_r, e);
                float w1b = __shfl(w1_r, e);
                float w = (p < 8) ? w0b : w1b;
                den += w;
                uint4 hv = ((const uint4*)h)[(size_t)src * 16 + p];
                float2 f0 = __half22float2(*(__half2*)&hv.x);
                float2 f1 = __half22float2(*(__half2*)&hv.y);
                float2 f2 = __half22float2(*(__half2*)&hv.z);
                float2 f3 = __half22float2(*(__half2*)&hv.w);
                acc0.x = fmaf(w, f0.x, acc0.x); acc0.y = fmaf(w, f0.y, acc0.y);
                acc0.z = fmaf(w, f1.x, acc0.z); acc0.w = fmaf(w, f1.y, acc0.w);
                acc1.x = fmaf(w, f2.x, acc1.x); acc1.y = fmaf(w, f2.y, acc1.y);
                acc1.z = fmaf(w, f3.x, acc1.z); acc1.w = fmaf(w, f3.y, acc1.w);
            }
        }
#pragma unroll
        for (int off = 16; off <= 32; off <<= 1) {
            acc0.x += __shfl_xor(acc0.x, off); acc0.y += __shfl_xor(acc0.y, off);
            acc0.z += __shfl_xor(acc0.z, off); acc0.w += __shfl_xor(acc0.w, off);
            acc1.x += __shfl_xor(acc1.x, off); acc1.y += __shfl_xor(acc1.y, off);
            acc1.z += __shfl_xor(acc1.z, off); acc1.w += __shfl_xor(acc1.w, off);
            den    += __shfl_xor(den, off);
        }
        if (lane < 16) {
            float inv = 1.f / den;
            float4 o0, o1;
            o0.x = acc0.x * inv + bv0.x; o0.y = acc0.y * inv + bv0.y;
            o0.z = acc0.z * inv + bv0.z; o0.w = acc0.w * inv + bv0.w;
            o1.x = acc1.x * inv + bv1.x; o1.y = acc1.y * inv + bv1.y;
            o1.z = acc1.z * inv + bv1.z; o1.w = acc1.w * inv + bv1.w;
            if (ELU) {
                o0.x = o0.x > 0.f ? o0.x : expm1f(o0.x);
                o0.y = o0.y > 0.f ? o0.y : expm1f(o0.y);
                o0.z = o0.z > 0.f ? o0.z : expm1f(o0.z);
                o0.w = o0.w > 0.f ? o0.w : expm1f(o0.w);
                o1.x = o1.x > 0.f ? o1.x : expm1f(o1.x);
                o1.y = o1.y > 0.f ? o1.y : expm1f(o1.y);
                o1.z = o1.z > 0.f ? o1.z : expm1f(o1.z);
                o1.w = o1.w > 0.f ? o1.w : expm1f(o1.w);
            }
            __half2 q0 = __floats2half2_rn(o0.x, o0.y);
            __half2 q1 = __floats2half2_rn(o0.z, o0.w);
            __half2 q2 = __floats2half2_rn(o1.x, o1.y);
            __half2 q3 = __floats2half2_rn(o1.z, o1.w);
            uint4 pk;
            pk.x = *(unsigned*)&q0; pk.y = *(unsigned*)&q1;
            pk.z = *(unsigned*)&q2; pk.w = *(unsigned*)&q3;
            ((uint4*)out)[(size_t)n * 16 + p] = pk;
        }
    }
}

__global__ __launch_bounds__(256)
void node_aggr1(const int* __restrict__ rowptr, const int* __restrict__ colsrc,
                const float* __restrict__ a_s, const float* __restrict__ a_d,
                const __half* __restrict__ h, const float* __restrict__ bias,
                const unsigned* __restrict__ Ms, float* __restrict__ out, int N) {
    int gw = (blockIdx.x * 256 + threadIdx.x) >> 6;
    int lane = threadIdx.x & 63;
    int nw = (gridDim.x * 256) >> 6;
    const int g = lane >> 3;
    const int p = lane & 7;
    const float AS = funmap(Ms[0]);
    float4 bv0 = ((const float4*)bias)[p * 2];
    float4 bv1 = ((const float4*)bias)[p * 2 + 1];

    for (int n = gw; n < N; n += nw) {
        const int b = rowptr[n], deg = rowptr[n + 1] - b;
        const float adn = a_d[n];
        float M = AS + adn; M = M > 0.f ? M : SLOPE * M;
        float den = 0.f;
        float4 acc0 = make_float4(0.f, 0.f, 0.f, 0.f);
        float4 acc1 = make_float4(0.f, 0.f, 0.f, 0.f);

        for (int c = 0; c < deg; c += 64) {
            int ii = c + lane;
            int src_r = 0;
            float w_r = 0.f;
            if (ii < deg) {
                src_r = colsrc[b + ii];
                float s = a_s[src_r] + adn;
                s = s > 0.f ? s : SLOPE * s;
                w_r = __expf(s - M);
            }
            int lim = (deg - c < 64) ? (deg - c) : 64;
#pragma unroll 2
            for (int i = 0; i < lim; i += 8) {
                int e = i + g;
                int src = __shfl(src_r, e);
                float w = __shfl(w_r, e);
                den += w;
                uint4 hv = ((const uint4*)h)[(size_t)src * 8 + p];
                float2 f0 = __half22float2(*(__half2*)&hv.x);
                float2 f1 = __half22float2(*(__half2*)&hv.y);
                float2 f2 = __half22float2(*(__half2*)&hv.z);
                float2 f3 = __half22float2(*(__half2*)&hv.w);
                acc0.x = fmaf(w, f0.x, acc0.x); acc0.y = fmaf(w, f0.y, acc0.y);
                acc0.z = fmaf(w, f1.x, acc0.z); acc0.w = fmaf(w, f1.y, acc0.w);
                acc1.x = fmaf(w, f2.x, acc1.x); acc1.y = fmaf(w, f2.y, acc1.y);
                acc1.z = fmaf(w, f3.x, acc1.z); acc1.w = fmaf(w, f3.y, acc1.w);
            }
        }
#pragma unroll
        for (int off = 8; off <= 32; off <<= 1) {
            acc0.x += __shfl_xor(acc0.x, off); acc0.y += __shfl_xor(acc0.y, off);
            acc0.z += __shfl_xor(acc0.z, off); acc0.w += __shfl_xor(acc0.w, off);
            acc1.x += __shfl_xor(acc1.x, off); acc1.y += __shfl_xor(acc1.y, off);
            acc1.z += __shfl_xor(acc1.z, off); acc1.w += __shfl_xor(acc1.w, off);
            den    += __shfl_xor(den, off);
        }
        if (lane < 8) {
            float inv = 1.f / den;
            float4 o0, o1;
            o0.x = acc0.x * inv + bv0.x; o0.y = acc0.y * inv + bv0.y;
            o0.z = acc0.z * inv + bv0.z; o0.w = acc0.w * inv + bv0.w;
            o1.x = acc1.x * inv + bv1.x; o1.y = acc1.y * inv + bv1.y;
            o1.z = acc1.z * inv + bv1.z; o1.w = acc1.w * inv + bv1.w;
            ((float4*)out)[(size_t)n * 16 + p * 2]     = o0;
            ((float4*)out)[(size_t)n * 16 + p * 2 + 1] = o1;
        }
    }
}

extern "C" void kernel_launch(void* const* d_in, const int* in_sizes, int n_in,
                              void* d_out, int out_size, void* d_ws, size_t ws_size,
                              hipStream_t stream) {
    const float* x   = (const float*)d_in[0];
    const int*   ei  = (const int*)d_in[1];
    const float* W1  = (const float*)d_in[2];
    const float* as1 = (const float*)d_in[3];
    const float* ad1 = (const float*)d_in[4];
    const float* b1  = (const float*)d_in[5];
    const float* W2  = (const float*)d_in[6];
    const float* as2 = (const float*)d_in[7];
    const float* ad2 = (const float*)d_in[8];
    const float* b2  = (const float*)d_in[9];
    float* out = (float*)d_out;

    const int N = out_size / 64;          // 100000
    const int E = in_sizes[1] / 2;        // 1600000
    const int Etot = E + N;
    const int nb = (N + 255) >> 8;        // 391

    float* ws   = (float*)d_ws;
    __half* h1  = (__half*)ws;
    __half* h1e = (__half*)(ws + (size_t)N * 64);
    float* a_s1 = ws + (size_t)N * 128;
    float* a_d1 = a_s1 + (size_t)N * 2;
    float* a_s2 = a_d1 + (size_t)N * 2;
    float* a_d2 = a_s2 + (size_t)N;
    int* rowptr = (int*)(a_d2 + (size_t)N);
    int* bnext  = rowptr + (N + 1);
    unsigned* Ms = (unsigned*)(bnext + 512);   // [0,1]=layer1, [2]=layer2
    int* colsrc = (int*)(Ms + 4);
    unsigned* pairs = (unsigned*)(colsrc + Etot);   // nb*BCAP u32 (~9.6MB)

    // zero bnext (512) + Ms (4) in one memset
    (void)hipMemsetAsync(bnext, 0, (512 + 4) * 4, stream);

    int cb = (Etot + CHUNK - 1) / CHUNK;        // 416
    const int GB = 512;                         // gemm blocks in fat kernel

    // ---- fat: bucket scatter || layer-1 MFMA GEMM ----
    fat1_k<<<dim3(cb + GB), dim3(256), 0, stream>>>(
        ei, E, Etot, bnext, pairs, nb, cb,
        x, W1, as1, ad1, h1, a_s1, a_d1, Ms, N, GB);
    fine_k<<<dim3(nb), dim3(1024), 0, stream>>>(
        pairs, bnext, rowptr, colsrc, nb, N, Etot);

    int ab = imin((N + 3) / 4, 25000);

    // ---- layer 1 aggregation ----
    node_aggr2<true><<<dim3(ab), dim3(256), 0, stream>>>(
        rowptr, colsrc, a_s1, a_d1, h1, b1, Ms, h1e, N);

    // ---- layer 2 ----
    __half* h2 = h1;   // h1 dead after node_aggr2
    gemm2_k<<<dim3(512), dim3(256), 0, stream>>>(
        h1e, W2, as2, ad2, h2, a_s2, a_d2, Ms + 2, N);
    node_aggr1<<<dim3(ab), dim3(256), 0, stream>>>(
        rowptr, colsrc, a_s2, a_d2, h2, b2, Ms + 2, out, N);
}

// Round 20
// 271.251 us; speedup vs baseline: 1.0689x; 1.0080x over previous
//
#include <hip/hip_runtime.h>
#include <hip/hip_bf16.h>
#include <hip/hip_fp16.h>
#include <math.h>

#define SLOPE 0.2f
#define CHUNK 4096
#define KSEG 16       // reservation sub-counters per bucket (chain 416 -> 26)
#define SUBCAP 768    // slots per (bucket, seg): worst ~512 (256 seq self-loops
                      // from ONE block + ~256 random), +12 sigma headroom

__host__ __device__ static inline int imin(int a, int b) { return a < b ? a : b; }

typedef _Float16 half8 __attribute__((ext_vector_type(8)));
typedef float f32x4 __attribute__((ext_vector_type(4)));

__device__ __forceinline__ unsigned fmap(float f) {
    unsigned u = __float_as_uint(f);
    return (u & 0x80000000u) ? ~u : (u | 0x80000000u);
}
__device__ __forceinline__ float funmap(unsigned u) {
    unsigned v = (u & 0x80000000u) ? (u & 0x7FFFFFFFu) : ~u;
    return __uint_as_float(v);
}

// ---------------- MFMA GEMM + attention dots + global AS-max (body) --------
template<int HC, typename TIN>
__device__ __forceinline__
void gemm_att_body(int bid, int nblk,
                   const TIN* __restrict__ x, const float* __restrict__ W,
                   const float* __restrict__ att_s, const float* __restrict__ att_d,
                   __half* __restrict__ h, float* __restrict__ a_s,
                   float* __restrict__ a_d, unsigned* __restrict__ Ms, int N) {
    constexpr int H = HC / 64;
    constexpr int CT = HC / 16;           // col tiles (8 or 4)
    __shared__ half8 blds[CT * 4 * 64];   // W fragments (32KB / 16KB)
    __shared__ half8 xlds[4 * 4 * 64];    // x fragments (16KB)

    const int tid = threadIdx.x;
    const int lane = tid & 63;
    const int wid = tid >> 6;

    for (int u = tid; u < HC * 16; u += 256) {
        int col = u & (HC - 1), k8 = u / HC;
        half8 v;
#pragma unroll
        for (int j = 0; j < 8; ++j) v[j] = (_Float16)W[(k8 * 8 + j) * HC + col];
        blds[((col >> 4) * 4 + (k8 >> 2)) * 64 + (k8 & 3) * 16 + (col & 15)] = v;
    }

    float asv[CT], adv[CT];
#pragma unroll
    for (int ct = 0; ct < CT; ++ct) {
        asv[ct] = att_s[ct * 16 + (lane & 15)];
        adv[ct] = att_d[ct * 16 + (lane & 15)];
    }
    float ms0 = -INFINITY, ms1 = -INFINITY;

    const int ntiles = (N + 63) >> 6;
    for (int t = bid; t < ntiles; t += nblk) {
        const int row0 = t << 6;
        __syncthreads();
#pragma unroll
        for (int i = 0; i < 4; ++i) {
            int u = tid + 256 * i;
            int r = u >> 4, k8 = u & 15;
            int row = row0 + r;
            half8 v;
            if (row < N) {
                if (sizeof(TIN) == 4) {
                    float4 f0 = ((const float4*)x)[(size_t)row * 32 + k8 * 2];
                    float4 f1 = ((const float4*)x)[(size_t)row * 32 + k8 * 2 + 1];
                    v[0] = (_Float16)f0.x; v[1] = (_Float16)f0.y;
                    v[2] = (_Float16)f0.z; v[3] = (_Float16)f0.w;
                    v[4] = (_Float16)f1.x; v[5] = (_Float16)f1.y;
                    v[6] = (_Float16)f1.z; v[7] = (_Float16)f1.w;
                } else {
                    v = ((const half8*)x)[(size_t)row * 16 + k8];
                }
            } else {
#pragma unroll
                for (int j = 0; j < 8; ++j) v[j] = (_Float16)0.f;
            }
            xlds[((r >> 4) * 4 + (k8 >> 2)) * 64 + (k8 & 3) * 16 + (r & 15)] = v;
        }
        __syncthreads();

        f32x4 acc[CT];
#pragma unroll
        for (int ct = 0; ct < CT; ++ct) acc[ct] = f32x4{0.f, 0.f, 0.f, 0.f};
        half8 afrag[4];
#pragma unroll
        for (int s = 0; s < 4; ++s) afrag[s] = xlds[(wid * 4 + s) * 64 + lane];
#pragma unroll
        for (int ct = 0; ct < CT; ++ct)
#pragma unroll
            for (int s = 0; s < 4; ++s)
                acc[ct] = __builtin_amdgcn_mfma_f32_16x16x32_f16(
                    afrag[s], blds[(ct * 4 + s) * 64 + lane], acc[ct], 0, 0, 0);

#pragma unroll
        for (int q = 0; q < 4; ++q) {
            int row = row0 + wid * 16 + (lane >> 4) * 4 + q;
            bool ok = row < N;
#pragma unroll
            for (int ct = 0; ct < CT; ++ct)
                if (ok) h[(size_t)row * HC + ct * 16 + (lane & 15)] =
                    __float2half((float)acc[ct][q]);
            float vs0 = 0.f, vd0 = 0.f, vs1 = 0.f, vd1 = 0.f;
#pragma unroll
            for (int ct = 0; ct < CT; ++ct) {
                float a = acc[ct][q];
                if (H == 2 && ct >= CT / 2) { vs1 = fmaf(a, asv[ct], vs1); vd1 = fmaf(a, adv[ct], vd1); }
                else                        { vs0 = fmaf(a, asv[ct], vs0); vd0 = fmaf(a, adv[ct], vd0); }
            }
#pragma unroll
            for (int off = 1; off < 16; off <<= 1) {
                vs0 += __shfl_xor(vs0, off); vd0 += __shfl_xor(vd0, off);
                if (H == 2) { vs1 += __shfl_xor(vs1, off); vd1 += __shfl_xor(vd1, off); }
            }
            if (ok) {
                ms0 = fmaxf(ms0, vs0);
                if (H == 2) ms1 = fmaxf(ms1, vs1);
                if ((lane & 15) == 0) {
                    if (H == 2) {
                        ((float2*)a_s)[row] = make_float2(vs0, vs1);
                        ((float2*)a_d)[row] = make_float2(vd0, vd1);
                    } else {
                        a_s[row] = vs0;
                        a_d[row] = vd0;
                    }
                }
            }
        }
    }
#pragma unroll
    for (int off = 1; off < 64; off <<= 1) {
        ms0 = fmaxf(ms0, __shfl_xor(ms0, off));
        if (H == 2) ms1 = fmaxf(ms1, __shfl_xor(ms1, off));
    }
    if (lane == 0) {
        atomicMax(&Ms[0], fmap(ms0));
        if (H == 2) atomicMax(&Ms[1], fmap(ms1));
    }
}

// ---------------- padded-bucket scatter body, 16-lane reservation ----------
__device__ __forceinline__
void bscatter_body(int bid, const int* __restrict__ ei, int E, int Etot,
                   int* __restrict__ bnext, unsigned* __restrict__ pairs, int nb) {
    __shared__ int lcnt[512];
    __shared__ int lbase[512];
    const int t = threadIdx.x;
    const int c0 = bid * CHUNK;
    const int lim = imin(CHUNK, Etot - c0);
    const int seg = bid & (KSEG - 1);

    for (int i = t; i < nb; i += 256) lcnt[i] = 0;
    __syncthreads();
    for (int j = t; j < lim; j += 256) {
        int e = c0 + j;
        int dst = (e < E) ? ei[E + e] : (e - E);
        atomicAdd(&lcnt[dst >> 8], 1);
    }
    __syncthreads();
    for (int i = t; i < nb; i += 256) {
        int c = lcnt[i];
        lbase[i] = c ? atomicAdd(&bnext[i * KSEG + seg], c) : 0;
        lcnt[i] = 0;   // reuse as cursor
    }
    __syncthreads();
    for (int j = t; j < lim; j += 256) {
        int e = c0 + j;
        int src = (e < E) ? ei[e] : (e - E);
        int dst = (e < E) ? ei[E + e] : (e - E);
        int b = dst >> 8;
        int off = atomicAdd(&lcnt[b], 1);
        pairs[((size_t)b * KSEG + seg) * SUBCAP + lbase[b] + off] =
            ((unsigned)(dst & 255) << 24) | (unsigned)src;
    }
}

// ---------------- fat kernel: bscatter (blocks [0,cb)) || gemm1 ------------
__global__ __launch_bounds__(256, 2)
void fat1_k(const int* __restrict__ ei, int E, int Etot,
            int* __restrict__ bnext, unsigned* __restrict__ pairs, int nb, int cb,
            const float* __restrict__ x, const float* __restrict__ W,
            const float* __restrict__ att_s, const float* __restrict__ att_d,
            __half* __restrict__ h, float* __restrict__ a_s,
            float* __restrict__ a_d, unsigned* __restrict__ Ms, int N, int gblk) {
    if ((int)blockIdx.x < cb)
        bscatter_body(blockIdx.x, ei, E, Etot, bnext, pairs, nb);
    else
        gemm_att_body<128, float>(blockIdx.x - cb, gblk, x, W, att_s, att_d,
                                  h, a_s, a_d, Ms, N);
}

__global__ __launch_bounds__(256, 2)
void gemm2_k(const __half* __restrict__ x, const float* __restrict__ W,
             const float* __restrict__ att_s, const float* __restrict__ att_d,
             __half* __restrict__ h, float* __restrict__ a_s,
             float* __restrict__ a_d, unsigned* __restrict__ Ms, int N) {
    gemm_att_body<64, __half>(blockIdx.x, gridDim.x, x, W, att_s, att_d,
                              h, a_s, a_d, Ms, N);
}

// one block per bucket, 1024 threads; iterates the KSEG sub-regions.
__global__ __launch_bounds__(1024)
void fine_k(const unsigned* __restrict__ pairs, const int* __restrict__ bnext,
            int* __restrict__ rowptr, int* __restrict__ colsrc,
            int nb, int N, int Etot) {
    __shared__ int sm[256];
    __shared__ int lnext[256];
    __shared__ int red[1024];
    const int b = blockIdx.x, t = threadIdx.x;

    int pacc = 0;
    for (int i = t; i < b * KSEG; i += 1024) pacc += bnext[i];
    red[t] = pacc; __syncthreads();
    for (int off = 512; off; off >>= 1) {
        if (t < off) red[t] += red[t + off];
        __syncthreads();
    }
    const int gbase = red[0];
    if (b == 0 && t == 0) rowptr[N] = Etot;

    if (t < 256) lnext[t] = 0;
    __syncthreads();
    for (int s = 0; s < KSEG; ++s) {
        int cnt = bnext[b * KSEG + s];
        const unsigned* ps = pairs + ((size_t)b * KSEG + s) * SUBCAP;
        for (int i = t; i < cnt; i += 1024)
            atomicAdd(&lnext[ps[i] >> 24], 1);
    }
    __syncthreads();
    int v = (t < 256) ? lnext[t] : 0;
    if (t < 256) sm[t] = v;
    __syncthreads();
    for (int off = 1; off < 256; off <<= 1) {
        int u = (t >= off && t < 256) ? sm[t - off] : 0;
        __syncthreads();
        if (t < 256) sm[t] += u;
        __syncthreads();
    }
    if (t < 256) {
        int excl = sm[t] - v;
        int node = (b << 8) + t;
        if (node < N) rowptr[node] = gbase + excl;
        lnext[t] = excl;
    }
    __syncthreads();
    for (int s = 0; s < KSEG; ++s) {
        int cnt = bnext[b * KSEG + s];
        const unsigned* ps = pairs + ((size_t)b * KSEG + s) * SUBCAP;
        for (int i = t; i < cnt; i += 1024) {
            unsigned pr = ps[i];
            int p = atomicAdd(&lnext[pr >> 24], 1);
            colsrc[gbase + p] = (int)(pr & 0xFFFFFFu);
        }
    }
}

// ---------------- per-node aggregation, edge-parallel lane groups ----------
template<bool ELU>
__global__ __launch_bounds__(256)
void node_aggr2(const int* __restrict__ rowptr, const int* __restrict__ colsrc,
                const float* __restrict__ a_s, const float* __restrict__ a_d,
                const __half* __restrict__ h, const float* __restrict__ bias,
                const unsigned* __restrict__ Ms, __half* __restrict__ out, int N) {
    int gw = (blockIdx.x * 256 + threadIdx.x) >> 6;
    int lane = threadIdx.x & 63;
    int nw = (gridDim.x * 256) >> 6;
    const int g = lane >> 4;
    const int p = lane & 15;
    const float AS0 = funmap(Ms[0]);
    const float AS1 = funmap(Ms[1]);
    float4 bv0 = ((const float4*)bias)[p * 2];
    float4 bv1 = ((const float4*)bias)[p * 2 + 1];

    for (int n = gw; n < N; n += nw) {
        const int b = rowptr[n], deg = rowptr[n + 1] - b;
        const float2 adn = ((const float2*)a_d)[n];
        float M0 = AS0 + adn.x; M0 = M0 > 0.f ? M0 : SLOPE * M0;
        float M1 = AS1 + adn.y; M1 = M1 > 0.f ? M1 : SLOPE * M1;
        float4 acc0 = make_float4(0.f, 0.f, 0.f, 0.f);
        float4 acc1 = make_float4(0.f, 0.f, 0.f, 0.f);
        float den = 0.f;

        for (int c = 0; c < deg; c += 64) {
            int ii = c + lane;
            int src_r = 0;
            float w0_r = 0.f, w1_r = 0.f;
            if (ii < deg) {
                src_r = colsrc[b + ii];
                float2 as = ((const float2*)a_s)[src_r];
                float s0 = as.x + adn.x; s0 = s0 > 0.f ? s0 : SLOPE * s0;
                float s1 = as.y + adn.y; s1 = s1 > 0.f ? s1 : SLOPE * s1;
                w0_r = __expf(s0 - M0);
                w1_r = __expf(s1 - M1);
            }
            int lim = (deg - c < 64) ? (deg - c) : 64;
#pragma unroll 2
            for (int i = 0; i < lim; i += 4) {
                int e = i + g;
                int src = __shfl(src_r, e);
                float w0b = __shfl(w0_r, e);
                float w1b = __shfl(w1_r, e);
                float w = (p < 8) ? w0b : w1b;
                den += w;
                uint4 hv = ((const uint4*)h)[(size_t)src * 16 + p];
                float2 f0 = __half22float2(*(__half2*)&hv.x);
                float2 f1 = __half22float2(*(__half2*)&hv.y);
                float2 f2 = __half22float2(*(__half2*)&hv.z);
                float2 f3 = __half22float2(*(__half2*)&hv.w);
                acc0.x = fmaf(w, f0.x, acc0.x); acc0.y = fmaf(w, f0.y, acc0.y);
                acc0.z = fmaf(w, f1.x, acc0.z); acc0.w = fmaf(w, f1.y, acc0.w);
                acc1.x = fmaf(w, f2.x, acc1.x); acc1.y = fmaf(w, f2.y, acc1.y);
                acc1.z = fmaf(w, f3.x, acc1.z); acc1.w = fmaf(w, f3.y, acc1.w);
            }
        }
#pragma unroll
        for (int off = 16; off <= 32; off <<= 1) {
            acc0.x += __shfl_xor(acc0.x, off); acc0.y += __shfl_xor(acc0.y, off);
            acc0.z += __shfl_xor(acc0.z, off); acc0.w += __shfl_xor(acc0.w, off);
            acc1.x += __shfl_xor(acc1.x, off); acc1.y += __shfl_xor(acc1.y, off);
            acc1.z += __shfl_xor(acc1.z, off); acc1.w += __shfl_xor(acc1.w, off);
            den    += __shfl_xor(den, off);
        }
        if (lane < 16) {
            float inv = 1.f / den;
            float4 o0, o1;
            o0.x = acc0.x * inv + bv0.x; o0.y = acc0.y * inv + bv0.y;
            o0.z = acc0.z * inv + bv0.z; o0.w = acc0.w * inv + bv0.w;
            o1.x = acc1.x * inv + bv1.x; o1.y = acc1.y * inv + bv1.y;
            o1.z = acc1.z * inv + bv1.z; o1.w = acc1.w * inv + bv1.w;
            if (ELU) {
                o0.x = o0.x > 0.f ? o0.x : expm1f(o0.x);
                o0.y = o0.y > 0.f ? o0.y : expm1f(o0.y);
                o0.z = o0.z > 0.f ? o0.z : expm1f(o0.z);
                o0.w = o0.w > 0.f ? o0.w : expm1f(o0.w);
                o1.x = o1.x > 0.f ? o1.x : expm1f(o1.x);
                o1.y = o1.y > 0.f ? o1.y : expm1f(o1.y);
                o1.z = o1.z > 0.f ? o1.z : expm1f(o1.z);
                o1.w = o1.w > 0.f ? o1.w : expm1f(o1.w);
            }
            __half2 q0 = __floats2half2_rn(o0.x, o0.y);
            __half2 q1 = __floats2half2_rn(o0.z, o0.w);
            __half2 q2 = __floats2half2_rn(o1.x, o1.y);
            __half2 q3 = __floats2half2_rn(o1.z, o1.w);
            uint4 pk;
            pk.x = *(unsigned*)&q0; pk.y = *(unsigned*)&q1;
            pk.z = *(unsigned*)&q2; pk.w = *(unsigned*)&q3;
            ((uint4*)out)[(size_t)n * 16 + p] = pk;
        }
    }
}

__global__ __launch_bounds__(256)
void node_aggr1(const int* __restrict__ rowptr, const int* __restrict__ colsrc,
                const float* __restrict__ a_s, const float* __restrict__ a_d,
                const __half* __restrict__ h, const float* __restrict__ bias,
                const unsigned* __restrict__ Ms, float* __restrict__ out, int N) {
    int gw = (blockIdx.x * 256 + threadIdx.x) >> 6;
    int lane = threadIdx.x & 63;
    int nw = (gridDim.x * 256) >> 6;
    const int g = lane >> 3;
    const int p = lane & 7;
    const float AS = funmap(Ms[0]);
    float4 bv0 = ((const float4*)bias)[p * 2];
    float4 bv1 = ((const float4*)bias)[p * 2 + 1];

    for (int n = gw; n < N; n += nw) {
        const int b = rowptr[n], deg = rowptr[n + 1] - b;
        const float adn = a_d[n];
        float M = AS + adn; M = M > 0.f ? M : SLOPE * M;
        float den = 0.f;
        float4 acc0 = make_float4(0.f, 0.f, 0.f, 0.f);
        float4 acc1 = make_float4(0.f, 0.f, 0.f, 0.f);

        for (int c = 0; c < deg; c += 64) {
            int ii = c + lane;
            int src_r = 0;
            float w_r = 0.f;
            if (ii < deg) {
                src_r = colsrc[b + ii];
                float s = a_s[src_r] + adn;
                s = s > 0.f ? s : SLOPE * s;
                w_r = __expf(s - M);
            }
            int lim = (deg - c < 64) ? (deg - c) : 64;
#pragma unroll 2
            for (int i = 0; i < lim; i += 8) {
                int e = i + g;
                int src = __shfl(src_r, e);
                float w = __shfl(w_r, e);
                den += w;
                uint4 hv = ((const uint4*)h)[(size_t)src * 8 + p];
                float2 f0 = __half22float2(*(__half2*)&hv.x);
                float2 f1 = __half22float2(*(__half2*)&hv.y);
                float2 f2 = __half22float2(*(__half2*)&hv.z);
                float2 f3 = __half22float2(*(__half2*)&hv.w);
                acc0.x = fmaf(w, f0.x, acc0.x); acc0.y = fmaf(w, f0.y, acc0.y);
                acc0.z = fmaf(w, f1.x, acc0.z); acc0.w = fmaf(w, f1.y, acc0.w);
                acc1.x = fmaf(w, f2.x, acc1.x); acc1.y = fmaf(w, f2.y, acc1.y);
                acc1.z = fmaf(w, f3.x, acc1.z); acc1.w = fmaf(w, f3.y, acc1.w);
            }
        }
#pragma unroll
        for (int off = 8; off <= 32; off <<= 1) {
            acc0.x += __shfl_xor(acc0.x, off); acc0.y += __shfl_xor(acc0.y, off);
            acc0.z += __shfl_xor(acc0.z, off); acc0.w += __shfl_xor(acc0.w, off);
            acc1.x += __shfl_xor(acc1.x, off); acc1.y += __shfl_xor(acc1.y, off);
            acc1.z += __shfl_xor(acc1.z, off); acc1.w += __shfl_xor(acc1.w, off);
            den    += __shfl_xor(den, off);
        }
        if (lane < 8) {
            float inv = 1.f / den;
            float4 o0, o1;
            o0.x = acc0.x * inv + bv0.x; o0.y = acc0.y * inv + bv0.y;
            o0.z = acc0.z * inv + bv0.z; o0.w = acc0.w * inv + bv0.w;
            o1.x = acc1.x * inv + bv1.x; o1.y = acc1.y * inv + bv1.y;
            o1.z = acc1.z * inv + bv1.z; o1.w = acc1.w * inv + bv1.w;
            ((float4*)out)[(size_t)n * 16 + p * 2]     = o0;
            ((float4*)out)[(size_t)n * 16 + p * 2 + 1] = o1;
        }
    }
}

extern "C" void kernel_launch(void* const* d_in, const int* in_sizes, int n_in,
                              void* d_out, int out_size, void* d_ws, size_t ws_size,
                              hipStream_t stream) {
    const float* x   = (const float*)d_in[0];
    const int*   ei  = (const int*)d_in[1];
    const float* W1  = (const float*)d_in[2];
    const float* as1 = (const float*)d_in[3];
    const float* ad1 = (const float*)d_in[4];
    const float* b1  = (const float*)d_in[5];
    const float* W2  = (const float*)d_in[6];
    const float* as2 = (const float*)d_in[7];
    const float* ad2 = (const float*)d_in[8];
    const float* b2  = (const float*)d_in[9];
    float* out = (float*)d_out;

    const int N = out_size / 64;          // 100000
    const int E = in_sizes[1] / 2;        // 1600000
    const int Etot = E + N;
    const int nb = (N + 255) >> 8;        // 391

    float* ws   = (float*)d_ws;
    __half* h1  = (__half*)ws;
    __half* h1e = (__half*)(ws + (size_t)N * 64);
    float* a_s1 = ws + (size_t)N * 128;
    float* a_d1 = a_s1 + (size_t)N * 2;
    float* a_s2 = a_d1 + (size_t)N * 2;
    float* a_d2 = a_s2 + (size_t)N;
    int* rowptr = (int*)(a_d2 + (size_t)N);
    int* bnext  = rowptr + (N + 1);            // nb*KSEG ints
    unsigned* Ms = (unsigned*)(bnext + nb * KSEG);  // [0,1]=layer1, [2]=layer2
    int* colsrc = (int*)(Ms + 4);
    unsigned* pairs = (unsigned*)(colsrc + Etot);   // nb*KSEG*SUBCAP u32 (~19MB)

    // zero bnext (nb*KSEG) + Ms (4) in one memset
    (void)hipMemsetAsync(bnext, 0, (size_t)(nb * KSEG + 4) * 4, stream);

    int cb = (Etot + CHUNK - 1) / CHUNK;        // 416
    const int GB = 512;                         // gemm blocks in fat kernel

    // ---- fat: bucket scatter || layer-1 MFMA GEMM ----
    fat1_k<<<dim3(cb + GB), dim3(256), 0, stream>>>(
        ei, E, Etot, bnext, pairs, nb, cb,
        x, W1, as1, ad1, h1, a_s1, a_d1, Ms, N, GB);
    fine_k<<<dim3(nb), dim3(1024), 0, stream>>>(
        pairs, bnext, rowptr, colsrc, nb, N, Etot);

    int ab = imin((N + 3) / 4, 25000);

    // ---- layer 1 aggregation ----
    node_aggr2<true><<<dim3(ab), dim3(256), 0, stream>>>(
        rowptr, colsrc, a_s1, a_d1, h1, b1, Ms, h1e, N);

    // ---- layer 2 ----
    __half* h2 = h1;   // h1 dead after node_aggr2
    gemm2_k<<<dim3(512), dim3(256), 0, stream>>>(
        h1e, W2, as2, ad2, h2, a_s2, a_d2, Ms + 2, N);
    node_aggr1<<<dim3(ab), dim3(256), 0, stream>>>(
        rowptr, colsrc, a_s2, a_d2, h2, b2, Ms + 2, out, N);
}

// Round 21
// 228.476 us; speedup vs baseline: 1.2690x; 1.1872x over previous
//
#include <hip/hip_runtime.h>
#include <hip/hip_bf16.h>
#include <hip/hip_fp16.h>
#include <math.h>

#define SLOPE 0.2f
#define CHUNK 4096
#define KSEG 16       // reservation sub-counters per bucket
#define SUBCAP 768    // slots per (bucket, seg)

__host__ __device__ static inline int imin(int a, int b) { return a < b ? a : b; }

typedef _Float16 half8 __attribute__((ext_vector_type(8)));
typedef float f32x4 __attribute__((ext_vector_type(4)));

__device__ __forceinline__ unsigned fmap(float f) {
    unsigned u = __float_as_uint(f);
    return (u & 0x80000000u) ? ~u : (u | 0x80000000u);
}
__device__ __forceinline__ float funmap(unsigned u) {
    unsigned v = (u & 0x80000000u) ? (u & 0x7FFFFFFFu) : ~u;
    return __uint_as_float(v);
}

// ---------------- MFMA GEMM + attention dots + global AS-max (body) --------
// AS-max: wave reduce -> LDS -> ONE atomicMax per block per head (was one per
// wave: 4096 same-address L2 RMWs serialized ~= the persistent ~90us fat1).
template<int HC, typename TIN>
__device__ __forceinline__
void gemm_att_body(int bid, int nblk,
                   const TIN* __restrict__ x, const float* __restrict__ W,
                   const float* __restrict__ att_s, const float* __restrict__ att_d,
                   __half* __restrict__ h, float* __restrict__ a_s,
                   float* __restrict__ a_d, unsigned* __restrict__ Ms, int N) {
    constexpr int H = HC / 64;
    constexpr int CT = HC / 16;           // col tiles (8 or 4)
    __shared__ half8 blds[CT * 4 * 64];   // W fragments (32KB / 16KB)
    __shared__ half8 xlds[4 * 4 * 64];    // x fragments (16KB)
    __shared__ float redm[8];

    const int tid = threadIdx.x;
    const int lane = tid & 63;
    const int wid = tid >> 6;

    for (int u = tid; u < HC * 16; u += 256) {
        int col = u & (HC - 1), k8 = u / HC;
        half8 v;
#pragma unroll
        for (int j = 0; j < 8; ++j) v[j] = (_Float16)W[(k8 * 8 + j) * HC + col];
        blds[((col >> 4) * 4 + (k8 >> 2)) * 64 + (k8 & 3) * 16 + (col & 15)] = v;
    }

    float asv[CT], adv[CT];
#pragma unroll
    for (int ct = 0; ct < CT; ++ct) {
        asv[ct] = att_s[ct * 16 + (lane & 15)];
        adv[ct] = att_d[ct * 16 + (lane & 15)];
    }
    float ms0 = -INFINITY, ms1 = -INFINITY;

    const int ntiles = (N + 63) >> 6;
    for (int t = bid; t < ntiles; t += nblk) {
        const int row0 = t << 6;
        __syncthreads();
#pragma unroll
        for (int i = 0; i < 4; ++i) {
            int u = tid + 256 * i;
            int r = u >> 4, k8 = u & 15;
            int row = row0 + r;
            half8 v;
            if (row < N) {
                if (sizeof(TIN) == 4) {
                    float4 f0 = ((const float4*)x)[(size_t)row * 32 + k8 * 2];
                    float4 f1 = ((const float4*)x)[(size_t)row * 32 + k8 * 2 + 1];
                    v[0] = (_Float16)f0.x; v[1] = (_Float16)f0.y;
                    v[2] = (_Float16)f0.z; v[3] = (_Float16)f0.w;
                    v[4] = (_Float16)f1.x; v[5] = (_Float16)f1.y;
                    v[6] = (_Float16)f1.z; v[7] = (_Float16)f1.w;
                } else {
                    v = ((const half8*)x)[(size_t)row * 16 + k8];
                }
            } else {
#pragma unroll
                for (int j = 0; j < 8; ++j) v[j] = (_Float16)0.f;
            }
            xlds[((r >> 4) * 4 + (k8 >> 2)) * 64 + (k8 & 3) * 16 + (r & 15)] = v;
        }
        __syncthreads();

        f32x4 acc[CT];
#pragma unroll
        for (int ct = 0; ct < CT; ++ct) acc[ct] = f32x4{0.f, 0.f, 0.f, 0.f};
        half8 afrag[4];
#pragma unroll
        for (int s = 0; s < 4; ++s) afrag[s] = xlds[(wid * 4 + s) * 64 + lane];
#pragma unroll
        for (int ct = 0; ct < CT; ++ct)
#pragma unroll
            for (int s = 0; s < 4; ++s)
                acc[ct] = __builtin_amdgcn_mfma_f32_16x16x32_f16(
                    afrag[s], blds[(ct * 4 + s) * 64 + lane], acc[ct], 0, 0, 0);

#pragma unroll
        for (int q = 0; q < 4; ++q) {
            int row = row0 + wid * 16 + (lane >> 4) * 4 + q;
            bool ok = row < N;
#pragma unroll
            for (int ct = 0; ct < CT; ++ct)
                if (ok) h[(size_t)row * HC + ct * 16 + (lane & 15)] =
                    __float2half((float)acc[ct][q]);
            float vs0 = 0.f, vd0 = 0.f, vs1 = 0.f, vd1 = 0.f;
#pragma unroll
            for (int ct = 0; ct < CT; ++ct) {
                float a = acc[ct][q];
                if (H == 2 && ct >= CT / 2) { vs1 = fmaf(a, asv[ct], vs1); vd1 = fmaf(a, adv[ct], vd1); }
                else                        { vs0 = fmaf(a, asv[ct], vs0); vd0 = fmaf(a, adv[ct], vd0); }
            }
#pragma unroll
            for (int off = 1; off < 16; off <<= 1) {
                vs0 += __shfl_xor(vs0, off); vd0 += __shfl_xor(vd0, off);
                if (H == 2) { vs1 += __shfl_xor(vs1, off); vd1 += __shfl_xor(vd1, off); }
            }
            if (ok) {
                ms0 = fmaxf(ms0, vs0);
                if (H == 2) ms1 = fmaxf(ms1, vs1);
                if ((lane & 15) == 0) {
                    if (H == 2) {
                        ((float2*)a_s)[row] = make_float2(vs0, vs1);
                        ((float2*)a_d)[row] = make_float2(vd0, vd1);
                    } else {
                        a_s[row] = vs0;
                        a_d[row] = vd0;
                    }
                }
            }
        }
    }
#pragma unroll
    for (int off = 1; off < 64; off <<= 1) {
        ms0 = fmaxf(ms0, __shfl_xor(ms0, off));
        if (H == 2) ms1 = fmaxf(ms1, __shfl_xor(ms1, off));
    }
    if (lane == 0) {
        redm[wid] = ms0;
        if (H == 2) redm[4 + wid] = ms1;
    }
    __syncthreads();
    if (tid == 0) {
        float m0 = fmaxf(fmaxf(redm[0], redm[1]), fmaxf(redm[2], redm[3]));
        atomicMax(&Ms[0], fmap(m0));
        if (H == 2) {
            float m1 = fmaxf(fmaxf(redm[4], redm[5]), fmaxf(redm[6], redm[7]));
            atomicMax(&Ms[1], fmap(m1));
        }
    }
}

// ---------------- padded-bucket scatter body, 16-lane reservation ----------
__device__ __forceinline__
void bscatter_body(int bid, const int* __restrict__ ei, int E, int Etot,
                   int* __restrict__ bnext, unsigned* __restrict__ pairs, int nb) {
    __shared__ int lcnt[512];
    __shared__ int lbase[512];
    const int t = threadIdx.x;
    const int c0 = bid * CHUNK;
    const int lim = imin(CHUNK, Etot - c0);
    const int seg = bid & (KSEG - 1);

    for (int i = t; i < nb; i += 256) lcnt[i] = 0;
    __syncthreads();
    for (int j = t; j < lim; j += 256) {
        int e = c0 + j;
        int dst = (e < E) ? ei[E + e] : (e - E);
        atomicAdd(&lcnt[dst >> 8], 1);
    }
    __syncthreads();
    for (int i = t; i < nb; i += 256) {
        int c = lcnt[i];
        lbase[i] = c ? atomicAdd(&bnext[i * KSEG + seg], c) : 0;
        lcnt[i] = 0;   // reuse as cursor
    }
    __syncthreads();
    for (int j = t; j < lim; j += 256) {
        int e = c0 + j;
        int src = (e < E) ? ei[e] : (e - E);
        int dst = (e < E) ? ei[E + e] : (e - E);
        int b = dst >> 8;
        int off = atomicAdd(&lcnt[b], 1);
        pairs[((size_t)b * KSEG + seg) * SUBCAP + lbase[b] + off] =
            ((unsigned)(dst & 255) << 24) | (unsigned)src;
    }
}

// ---------------- fat kernel: bscatter (blocks [0,cb)) || gemm1 ------------
__global__ __launch_bounds__(256, 2)
void fat1_k(const int* __restrict__ ei, int E, int Etot,
            int* __restrict__ bnext, unsigned* __restrict__ pairs, int nb, int cb,
            const float* __restrict__ x, const float* __restrict__ W,
            const float* __restrict__ att_s, const float* __restrict__ att_d,
            __half* __restrict__ h, float* __restrict__ a_s,
            float* __restrict__ a_d, unsigned* __restrict__ Ms, int N, int gblk) {
    if ((int)blockIdx.x < cb)
        bscatter_body(blockIdx.x, ei, E, Etot, bnext, pairs, nb);
    else
        gemm_att_body<128, float>(blockIdx.x - cb, gblk, x, W, att_s, att_d,
                                  h, a_s, a_d, Ms, N);
}

__global__ __launch_bounds__(256, 2)
void gemm2_k(const __half* __restrict__ x, const float* __restrict__ W,
             const float* __restrict__ att_s, const float* __restrict__ att_d,
             __half* __restrict__ h, float* __restrict__ a_s,
             float* __restrict__ a_d, unsigned* __restrict__ Ms, int N) {
    gemm_att_body<64, __half>(blockIdx.x, gridDim.x, x, W, att_s, att_d,
                              h, a_s, a_d, Ms, N);
}

// one block per bucket, 1024 threads; iterates the KSEG sub-regions.
__global__ __launch_bounds__(1024)
void fine_k(const unsigned* __restrict__ pairs, const int* __restrict__ bnext,
            int* __restrict__ rowptr, int* __restrict__ colsrc,
            int nb, int N, int Etot) {
    __shared__ int sm[256];
    __shared__ int lnext[256];
    __shared__ int red[1024];
    const int b = blockIdx.x, t = threadIdx.x;

    int pacc = 0;
    for (int i = t; i < b * KSEG; i += 1024) pacc += bnext[i];
    red[t] = pacc; __syncthreads();
    for (int off = 512; off; off >>= 1) {
        if (t < off) red[t] += red[t + off];
        __syncthreads();
    }
    const int gbase = red[0];
    if (b == 0 && t == 0) rowptr[N] = Etot;

    if (t < 256) lnext[t] = 0;
    __syncthreads();
    for (int s = 0; s < KSEG; ++s) {
        int cnt = bnext[b * KSEG + s];
        const unsigned* ps = pairs + ((size_t)b * KSEG + s) * SUBCAP;
        for (int i = t; i < cnt; i += 1024)
            atomicAdd(&lnext[ps[i] >> 24], 1);
    }
    __syncthreads();
    int v = (t < 256) ? lnext[t] : 0;
    if (t < 256) sm[t] = v;
    __syncthreads();
    for (int off = 1; off < 256; off <<= 1) {
        int u = (t >= off && t < 256) ? sm[t - off] : 0;
        __syncthreads();
        if (t < 256) sm[t] += u;
        __syncthreads();
    }
    if (t < 256) {
        int excl = sm[t] - v;
        int node = (b << 8) + t;
        if (node < N) rowptr[node] = gbase + excl;
        lnext[t] = excl;
    }
    __syncthreads();
    for (int s = 0; s < KSEG; ++s) {
        int cnt = bnext[b * KSEG + s];
        const unsigned* ps = pairs + ((size_t)b * KSEG + s) * SUBCAP;
        for (int i = t; i < cnt; i += 1024) {
            unsigned pr = ps[i];
            int p = atomicAdd(&lnext[pr >> 24], 1);
            colsrc[gbase + p] = (int)(pr & 0xFFFFFFu);
        }
    }
}

// ---------------- per-node aggregation, edge-parallel lane groups ----------
template<bool ELU>
__global__ __launch_bounds__(256)
void node_aggr2(const int* __restrict__ rowptr, const int* __restrict__ colsrc,
                const float* __restrict__ a_s, const float* __restrict__ a_d,
                const __half* __restrict__ h, const float* __restrict__ bias,
                const unsigned* __restrict__ Ms, __half* __restrict__ out, int N) {
    int gw = (blockIdx.x * 256 + threadIdx.x) >> 6;
    int lane = threadIdx.x & 63;
    int nw = (gridDim.x * 256) >> 6;
    const int g = lane >> 4;
    const int p = lane & 15;
    const float AS0 = funmap(Ms[0]);
    const float AS1 = funmap(Ms[1]);
    float4 bv0 = ((const float4*)bias)[p * 2];
    float4 bv1 = ((const float4*)bias)[p * 2 + 1];

    for (int n = gw; n < N; n += nw) {
        const int b = rowptr[n], deg = rowptr[n + 1] - b;
        const float2 adn = ((const float2*)a_d)[n];
        float M0 = AS0 + adn.x; M0 = M0 > 0.f ? M0 : SLOPE * M0;
        float M1 = AS1 + adn.y; M1 = M1 > 0.f ? M1 : SLOPE * M1;
        float4 acc0 = make_float4(0.f, 0.f, 0.f, 0.f);
        float4 acc1 = make_float4(0.f, 0.f, 0.f, 0.f);
        float den = 0.f;

        for (int c = 0; c < deg; c += 64) {
            int ii = c + lane;
            int src_r = 0;
            float w0_r = 0.f, w1_r = 0.f;
            if (ii < deg) {
                src_r = colsrc[b + ii];
                float2 as = ((const float2*)a_s)[src_r];
                float s0 = as.x + adn.x; s0 = s0 > 0.f ? s0 : SLOPE * s0;
                float s1 = as.y + adn.y; s1 = s1 > 0.f ? s1 : SLOPE * s1;
                w0_r = __expf(s0 - M0);
                w1_r = __expf(s1 - M1);
            }
            int lim = (deg - c < 64) ? (deg - c) : 64;
#pragma unroll 2
            for (int i = 0; i < lim; i += 4) {
                int e = i + g;
                int src = __shfl(src_r, e);
                float w0b = __shfl(w0_r, e);
                float w1b = __shfl(w1_r, e);
                float w = (p < 8) ? w0b : w1b;
                den += w;
                uint4 hv = ((const uint4*)h)[(size_t)src * 16 + p];
                float2 f0 = __half22float2(*(__half2*)&hv.x);
                float2 f1 = __half22float2(*(__half2*)&hv.y);
                float2 f2 = __half22float2(*(__half2*)&hv.z);
                float2 f3 = __half22float2(*(__half2*)&hv.w);
                acc0.x = fmaf(w, f0.x, acc0.x); acc0.y = fmaf(w, f0.y, acc0.y);
                acc0.z = fmaf(w, f1.x, acc0.z); acc0.w = fmaf(w, f1.y, acc0.w);
                acc1.x = fmaf(w, f2.x, acc1.x); acc1.y = fmaf(w, f2.y, acc1.y);
                acc1.z = fmaf(w, f3.x, acc1.z); acc1.w = fmaf(w, f3.y, acc1.w);
            }
        }
#pragma unroll
        for (int off = 16; off <= 32; off <<= 1) {
            acc0.x += __shfl_xor(acc0.x, off); acc0.y += __shfl_xor(acc0.y, off);
            acc0.z += __shfl_xor(acc0.z, off); acc0.w += __shfl_xor(acc0.w, off);
            acc1.x += __shfl_xor(acc1.x, off); acc1.y += __shfl_xor(acc1.y, off);
            acc1.z += __shfl_xor(acc1.z, off); acc1.w += __shfl_xor(acc1.w, off);
            den    += __shfl_xor(den, off);
        }
        if (lane < 16) {
            float inv = 1.f / den;
            float4 o0, o1;
            o0.x = acc0.x * inv + bv0.x; o0.y = acc0.y * inv + bv0.y;
            o0.z = acc0.z * inv + bv0.z; o0.w = acc0.w * inv + bv0.w;
            o1.x = acc1.x * inv + bv1.x; o1.y = acc1.y * inv + bv1.y;
            o1.z = acc1.z * inv + bv1.z; o1.w = acc1.w * inv + bv1.w;
            if (ELU) {
                o0.x = o0.x > 0.f ? o0.x : expm1f(o0.x);
                o0.y = o0.y > 0.f ? o0.y : expm1f(o0.y);
                o0.z = o0.z > 0.f ? o0.z : expm1f(o0.z);
                o0.w = o0.w > 0.f ? o0.w : expm1f(o0.w);
                o1.x = o1.x > 0.f ? o1.x : expm1f(o1.x);
                o1.y = o1.y > 0.f ? o1.y : expm1f(o1.y);
                o1.z = o1.z > 0.f ? o1.z : expm1f(o1.z);
                o1.w = o1.w > 0.f ? o1.w : expm1f(o1.w);
            }
            __half2 q0 = __floats2half2_rn(o0.x, o0.y);
            __half2 q1 = __floats2half2_rn(o0.z, o0.w);
            __half2 q2 = __floats2half2_rn(o1.x, o1.y);
            __half2 q3 = __floats2half2_rn(o1.z, o1.w);
            uint4 pk;
            pk.x = *(unsigned*)&q0; pk.y = *(unsigned*)&q1;
            pk.z = *(unsigned*)&q2; pk.w = *(unsigned*)&q3;
            ((uint4*)out)[(size_t)n * 16 + p] = pk;
        }
    }
}

__global__ __launch_bounds__(256)
void node_aggr1(const int* __restrict__ rowptr, const int* __restrict__ colsrc,
                const float* __restrict__ a_s, const float* __restrict__ a_d,
                const __half* __restrict__ h, const float* __restrict__ bias,
                const unsigned* __restrict__ Ms, float* __restrict__ out, int N) {
    int gw = (blockIdx.x * 256 + threadIdx.x) >> 6;
    int lane = threadIdx.x & 63;
    int nw = (gridDim.x * 256) >> 6;
    const int g = lane >> 3;
    const int p = lane & 7;
    const float AS = funmap(Ms[0]);
    float4 bv0 = ((const float4*)bias)[p * 2];
    float4 bv1 = ((const float4*)bias)[p * 2 + 1];

    for (int n = gw; n < N; n += nw) {
        const int b = rowptr[n], deg = rowptr[n + 1] - b;
        const float adn = a_d[n];
        float M = AS + adn; M = M > 0.f ? M : SLOPE * M;
        float den = 0.f;
        float4 acc0 = make_float4(0.f, 0.f, 0.f, 0.f);
        float4 acc1 = make_float4(0.f, 0.f, 0.f, 0.f);

        for (int c = 0; c < deg; c += 64) {
            int ii = c + lane;
            int src_r = 0;
            float w_r = 0.f;
            if (ii < deg) {
                src_r = colsrc[b + ii];
                float s = a_s[src_r] + adn;
                s = s > 0.f ? s : SLOPE * s;
                w_r = __expf(s - M);
            }
            int lim = (deg - c < 64) ? (deg - c) : 64;
#pragma unroll 2
            for (int i = 0; i < lim; i += 8) {
                int e = i + g;
                int src = __shfl(src_r, e);
                float w = __shfl(w_r, e);
                den += w;
                uint4 hv = ((const uint4*)h)[(size_t)src * 8 + p];
                float2 f0 = __half22float2(*(__half2*)&hv.x);
                float2 f1 = __half22float2(*(__half2*)&hv.y);
                float2 f2 = __half22float2(*(__half2*)&hv.z);
                float2 f3 = __half22float2(*(__half2*)&hv.w);
                acc0.x = fmaf(w, f0.x, acc0.x); acc0.y = fmaf(w, f0.y, acc0.y);
                acc0.z = fmaf(w, f1.x, acc0.z); acc0.w = fmaf(w, f1.y, acc0.w);
                acc1.x = fmaf(w, f2.x, acc1.x); acc1.y = fmaf(w, f2.y, acc1.y);
                acc1.z = fmaf(w, f3.x, acc1.z); acc1.w = fmaf(w, f3.y, acc1.w);
            }
        }
#pragma unroll
        for (int off = 8; off <= 32; off <<= 1) {
            acc0.x += __shfl_xor(acc0.x, off); acc0.y += __shfl_xor(acc0.y, off);
            acc0.z += __shfl_xor(acc0.z, off); acc0.w += __shfl_xor(acc0.w, off);
            acc1.x += __shfl_xor(acc1.x, off); acc1.y += __shfl_xor(acc1.y, off);
            acc1.z += __shfl_xor(acc1.z, off); acc1.w += __shfl_xor(acc1.w, off);
            den    += __shfl_xor(den, off);
        }
        if (lane < 8) {
            float inv = 1.f / den;
            float4 o0, o1;
            o0.x = acc0.x * inv + bv0.x; o0.y = acc0.y * inv + bv0.y;
            o0.z = acc0.z * inv + bv0.z; o0.w = acc0.w * inv + bv0.w;
            o1.x = acc1.x * inv + bv1.x; o1.y = acc1.y * inv + bv1.y;
            o1.z = acc1.z * inv + bv1.z; o1.w = acc1.w * inv + bv1.w;
            ((float4*)out)[(size_t)n * 16 + p * 2]     = o0;
            ((float4*)out)[(size_t)n * 16 + p * 2 + 1] = o1;
        }
    }
}

extern "C" void kernel_launch(void* const* d_in, const int* in_sizes, int n_in,
                              void* d_out, int out_size, void* d_ws, size_t ws_size,
                              hipStream_t stream) {
    const float* x   = (const float*)d_in[0];
    const int*   ei  = (const int*)d_in[1];
    const float* W1  = (const float*)d_in[2];
    const float* as1 = (const float*)d_in[3];
    const float* ad1 = (const float*)d_in[4];
    const float* b1  = (const float*)d_in[5];
    const float* W2  = (const float*)d_in[6];
    const float* as2 = (const float*)d_in[7];
    const float* ad2 = (const float*)d_in[8];
    const float* b2  = (const float*)d_in[9];
    float* out = (float*)d_out;

    const int N = out_size / 64;          // 100000
    const int E = in_sizes[1] / 2;        // 1600000
    const int Etot = E + N;
    const int nb = (N + 255) >> 8;        // 391

    float* ws   = (float*)d_ws;
    __half* h1  = (__half*)ws;
    __half* h1e = (__half*)(ws + (size_t)N * 64);
    float* a_s1 = ws + (size_t)N * 128;
    float* a_d1 = a_s1 + (size_t)N * 2;
    float* a_s2 = a_d1 + (size_t)N * 2;
    float* a_d2 = a_s2 + (size_t)N;
    int* rowptr = (int*)(a_d2 + (size_t)N);
    int* bnext  = rowptr + (N + 1);            // nb*KSEG ints
    unsigned* Ms = (unsigned*)(bnext + nb * KSEG);  // [0,1]=layer1, [2]=layer2
    int* colsrc = (int*)(Ms + 4);
    unsigned* pairs = (unsigned*)(colsrc + Etot);   // nb*KSEG*SUBCAP u32 (~19MB)

    // zero bnext (nb*KSEG) + Ms (4) in one memset
    (void)hipMemsetAsync(bnext, 0, (size_t)(nb * KSEG + 4) * 4, stream);

    int cb = (Etot + CHUNK - 1) / CHUNK;        // 416
    const int GB = 512;                         // gemm blocks in fat kernel

    // ---- fat: bucket scatter || layer-1 MFMA GEMM ----
    fat1_k<<<dim3(cb + GB), dim3(256), 0, stream>>>(
        ei, E, Etot, bnext, pairs, nb, cb,
        x, W1, as1, ad1, h1, a_s1, a_d1, Ms, N, GB);
    fine_k<<<dim3(nb), dim3(1024), 0, stream>>>(
        pairs, bnext, rowptr, colsrc, nb, N, Etot);

    int ab = imin((N + 3) / 4, 25000);

    // ---- layer 1 aggregation ----
    node_aggr2<true><<<dim3(ab), dim3(256), 0, stream>>>(
        rowptr, colsrc, a_s1, a_d1, h1, b1, Ms, h1e, N);

    // ---- layer 2 ----
    __half* h2 = h1;   // h1 dead after node_aggr2
    gemm2_k<<<dim3(512), dim3(256), 0, stream>>>(
        h1e, W2, as2, ad2, h2, a_s2, a_d2, Ms + 2, N);
    node_aggr1<<<dim3(ab), dim3(256), 0, stream>>>(
        rowptr, colsrc, a_s2, a_d2, h2, b2, Ms + 2, out, N);
}